// Round 3
// baseline (2122.990 us; speedup 1.0000x reference)
//
#include <hip/hip_runtime.h>
#include <stdint.h>

#define NROWS 131072
#define NC 1024
#define ND 512
#define BM 64
#define NSTEP 32   // 16 K-steps for B-hi pass + 16 for B-lo pass

using f32x4   = __attribute__((ext_vector_type(4))) float;
using bf16x8  = __attribute__((ext_vector_type(8))) short;
using short2v = __attribute__((ext_vector_type(2))) short;
using float2v = __attribute__((ext_vector_type(2))) float;
using float4v = __attribute__((ext_vector_type(4))) float;

__device__ __forceinline__ uint16_t f32_bf16(float f) {
  uint32_t u = __builtin_bit_cast(uint32_t, f);
  u += 0x7FFFu + ((u >> 16) & 1u);   // RNE
  return (uint16_t)(u >> 16);
}
__device__ __forceinline__ float bf16_f32(uint16_t h) {
  uint32_t u = ((uint32_t)h) << 16;
  return __builtin_bit_cast(float, u);
}

__device__ __forceinline__ void gload_lds16(const void* g, void* l) {
  __builtin_amdgcn_global_load_lds(
      (const __attribute__((address_space(1))) unsigned int*)g,
      (__attribute__((address_space(3))) unsigned int*)l, 16, 0, 0);
}

// ---------------------------------------------------------------------------
// Prep: split centers into bf16 hi/lo, pre-permuted so that each K-step slice
// is a contiguous 64KB block whose LINEAR copy into LDS yields the swizzled
// layout: LDS[c*64 + p*16 + b] holds logical chunk j = p ^ (c&3) of row c.
// Also computes csq[c] = sum(c^2) in fp32.
// ---------------------------------------------------------------------------
__global__ __launch_bounds__(64) void prep_centers(
    const float* __restrict__ centers,
    uint16_t* __restrict__ cs_hi, uint16_t* __restrict__ cs_lo,
    float* __restrict__ csq) {
  const int c = blockIdx.x;   // 1024
  const int t = threadIdx.x;  // 64
  const float* row = centers + (size_t)c * ND;
  const int k0 = t * 8;
  float v[8];
#pragma unroll
  for (int i = 0; i < 8; ++i) v[i] = row[k0 + i];
  float ss = 0.f;
#pragma unroll
  for (int i = 0; i < 8; ++i) ss += v[i] * v[i];
#pragma unroll
  for (int m = 1; m < 64; m <<= 1) ss += __shfl_xor(ss, m);
  if (t == 0) csq[c] = ss;

  const int kk = t >> 2;          // K-step 0..15
  const int j  = t & 3;           // logical 16B chunk within K-step
  const int p  = j ^ (c & 3);     // physical chunk (XOR swizzle)
  const size_t off = (size_t)kk * 32768 + (size_t)c * 32 + (size_t)p * 8;
#pragma unroll
  for (int i = 0; i < 8; ++i) {
    uint16_t h = f32_bf16(v[i]);
    uint16_t l = f32_bf16(v[i] - bf16_f32(h));
    cs_hi[off + i] = h;
    cs_lo[off + i] = l;
  }
}

// ---------------------------------------------------------------------------
// Fused kernel: 64 rows x full 1024 cols per block. 16 waves (2 wm x 8 wn),
// wave tile 32x128, mfma_f32_16x16x32_bf16. Two passes over K:
//   pass H (s<16): B = cs_hi, acc += a_hi*b + a_lo*b
//   pass L (s>=16): B = cs_lo, acc += a_hi*b
// Epilogue: transpose C-tile through LDS (reusing bs), one wave per output
// row -> row-local softmax + 1KB-contiguous float4 stores for dist and prob.
// ---------------------------------------------------------------------------
__global__ __launch_bounds__(1024, 4) void kmeans_fused(
    const float* __restrict__ x,
    const uint16_t* __restrict__ cs_hi, const uint16_t* __restrict__ cs_lo,
    const float* __restrict__ csq,
    float* __restrict__ dist, float* __restrict__ prob) {
  __shared__ __align__(16) char bs[2][65536];     // 1024 cols x 32 bf16, swizzled
  __shared__ __align__(16) char as_hi[2][4096];   // 64 rows x 32 bf16, swizzled
  __shared__ __align__(16) char as_lo[2][4096];
  __shared__ float xsq[BM];

  const int tid  = threadIdx.x;
  const int lane = tid & 63;
  const int wid  = tid >> 6;   // 0..15
  const int wm   = wid >> 3;   // 0..1 -> rows wm*32
  const int wn   = wid & 7;    // 0..7 -> cols wn*128
  const int row0 = blockIdx.x * BM;

  // ---- xsq (exact fp32): 16 threads per row, 32 elems each ----
  {
    const int r = tid >> 4, sub = tid & 15;
    const float* rp = x + (size_t)(row0 + r) * ND + sub * 32;
    float ss = 0.f;
#pragma unroll
    for (int i = 0; i < 8; ++i) {
      float4v v = *(const float4v*)(rp + i * 4);
      ss += v[0] * v[0] + v[1] * v[1] + v[2] * v[2] + v[3] * v[3];
    }
    ss += __shfl_xor(ss, 1);
    ss += __shfl_xor(ss, 2);
    ss += __shfl_xor(ss, 4);
    ss += __shfl_xor(ss, 8);
    if (sub == 0) xsq[r] = ss;
  }

  auto stage = [&](int s) {
    const uint16_t* src = (s < 16 ? cs_hi : cs_lo) + (size_t)(s & 15) * 32768;
    const char* srcb = (const char*)src;
    char* dst = bs[s & 1];
#pragma unroll
    for (int i = 0; i < 4; ++i) {
      const int o = (tid + i * 1024) * 16;
      gload_lds16(srcb + o, dst + o);
    }
  };
  auto xload = [&](int s) -> float2v {
    const int r = tid >> 4, c = tid & 15;
    return *(const float2v*)(x + (size_t)(row0 + r) * ND + (s & 15) * 32 + c * 2);
  };
  auto awrite = [&](int s, float2v v) {
    const int r = tid >> 4, c = tid & 15;
    const int p = (c >> 2) ^ (r & 3);
    const int off = r * 64 + p * 16 + (c & 3) * 4;
    short2v h, l;
#pragma unroll
    for (int i = 0; i < 2; ++i) {
      uint16_t hb = f32_bf16(v[i]);
      h[i] = (short)hb;
      l[i] = (short)f32_bf16(v[i] - bf16_f32(hb));
    }
    *(short2v*)(as_hi[s & 1] + off) = h;
    *(short2v*)(as_lo[s & 1] + off) = l;
  };

  f32x4 acc[2][8];
  const f32x4 z = {0.f, 0.f, 0.f, 0.f};
#pragma unroll
  for (int mr = 0; mr < 2; ++mr)
#pragma unroll
    for (int n = 0; n < 8; ++n) acc[mr][n] = z;

  // fragment LDS byte offsets (row&3 == lane&3 since bases are mult of 16)
  const int swz  = (((lane >> 4) ^ (lane & 3)) << 4);
  const int aoff = (wm * 32 + (lane & 15)) * 64 + swz;   // + mr*1024
  const int boff = (wn * 128 + (lane & 15)) * 64 + swz;  // + n*1024

  auto compute = [&](int s) {
    const char* bp  = bs[s & 1];
    const char* ahp = as_hi[s & 1];
    bf16x8 ah0 = *(const bf16x8*)(ahp + aoff);
    bf16x8 ah1 = *(const bf16x8*)(ahp + aoff + 1024);
    if (s < 16) {
      const char* alp = as_lo[s & 1];
      bf16x8 al0 = *(const bf16x8*)(alp + aoff);
      bf16x8 al1 = *(const bf16x8*)(alp + aoff + 1024);
#pragma unroll
      for (int n = 0; n < 8; ++n) {
        bf16x8 b = *(const bf16x8*)(bp + boff + n * 1024);
        acc[0][n] = __builtin_amdgcn_mfma_f32_16x16x32_bf16(ah0, b, acc[0][n], 0, 0, 0);
        acc[1][n] = __builtin_amdgcn_mfma_f32_16x16x32_bf16(ah1, b, acc[1][n], 0, 0, 0);
        acc[0][n] = __builtin_amdgcn_mfma_f32_16x16x32_bf16(al0, b, acc[0][n], 0, 0, 0);
        acc[1][n] = __builtin_amdgcn_mfma_f32_16x16x32_bf16(al1, b, acc[1][n], 0, 0, 0);
      }
    } else {
#pragma unroll
      for (int n = 0; n < 8; ++n) {
        bf16x8 b = *(const bf16x8*)(bp + boff + n * 1024);
        acc[0][n] = __builtin_amdgcn_mfma_f32_16x16x32_bf16(ah0, b, acc[0][n], 0, 0, 0);
        acc[1][n] = __builtin_amdgcn_mfma_f32_16x16x32_bf16(ah1, b, acc[1][n], 0, 0, 0);
      }
    }
  };

  // ---- main loop: double-buffered Bs (global_load_lds) + reg-staged As ----
  stage(0);
  {
    float2v v0 = xload(0);
    awrite(0, v0);
  }
  __syncthreads();
#pragma unroll 1
  for (int s = 0; s < NSTEP; ++s) {
    if (s + 1 < NSTEP) {
      stage(s + 1);
      float2v vn = xload(s + 1);
      compute(s);
      awrite(s + 1, vn);
    } else {
      compute(s);
    }
    __syncthreads();
  }

  // ---- epilogue: LDS transpose (16 rows/pass) + row-local softmax ----
  float* ldsT = (float*)&bs[0][0];   // 16 x 1024 fp32 = 64KB
  const int rsub = (lane >> 4) * 4;
#pragma unroll
  for (int p = 0; p < 4; ++p) {
    if (wm == (p >> 1)) {
      const int mr = p & 1;
#pragma unroll
      for (int n = 0; n < 8; ++n)
#pragma unroll
        for (int r = 0; r < 4; ++r) {
          const int lrow = rsub + r;
          const int col = wn * 128 + (lane & 15) + n * 16;
          ldsT[lrow * 1024 + (col ^ (((lrow >> 2) & 3) << 3))] = acc[mr][n][r];
        }
    }
    __syncthreads();
    {
      const int lrow = wid;                 // one wave per row
      const size_t grow = (size_t)(row0 + p * 16 + lrow);
      const int cmask = ((lrow >> 2) & 3) << 3;
      const float xq = xsq[p * 16 + lrow];
      float4v dd[4];
      float dmin = 1e30f;
#pragma unroll
      for (int j = 0; j < 4; ++j) {
        const int f = lane * 4 + j * 256;
        float4v raw = *(const float4v*)&ldsT[lrow * 1024 + (f ^ cmask)];
        float4v cq = *(const float4v*)(csq + f);
#pragma unroll
        for (int i = 0; i < 4; ++i) {
          float d = fmaxf(xq + cq[i] - 2.0f * raw[i], 0.0f);
          dd[j][i] = d;
          dmin = fminf(dmin, d);
        }
      }
#pragma unroll
      for (int m = 1; m < 64; m <<= 1) dmin = fminf(dmin, __shfl_xor(dmin, m));
      // store distances (1KB contiguous per instruction)
#pragma unroll
      for (int j = 0; j < 4; ++j)
        *(float4v*)(dist + grow * NC + lane * 4 + j * 256) = dd[j];
      // exp + sum (overwrite dd with e)
      float ssum = 0.f;
#pragma unroll
      for (int j = 0; j < 4; ++j)
#pragma unroll
        for (int i = 0; i < 4; ++i) {
          float e = __expf(dmin - dd[j][i]);
          dd[j][i] = e;
          ssum += e;
        }
#pragma unroll
      for (int m = 1; m < 64; m <<= 1) ssum += __shfl_xor(ssum, m);
      const float sinv = 1.0f / ssum;
#pragma unroll
      for (int j = 0; j < 4; ++j) {
        float4v pv;
#pragma unroll
        for (int i = 0; i < 4; ++i) pv[i] = dd[j][i] * sinv;
        *(float4v*)(prob + grow * NC + lane * 4 + j * 256) = pv;
      }
    }
    __syncthreads();
  }
}

extern "C" void kernel_launch(void* const* d_in, const int* in_sizes, int n_in,
                              void* d_out, int out_size, void* d_ws, size_t ws_size,
                              hipStream_t stream) {
  const float* x = (const float*)d_in[0];
  const float* centers = (const float*)d_in[1];
  float* dist = (float*)d_out;
  float* prob = dist + (size_t)NROWS * NC;

  uint16_t* cs_hi = (uint16_t*)d_ws;                 // 1 MB
  uint16_t* cs_lo = cs_hi + (size_t)NC * ND;         // 1 MB
  float* csq = (float*)(cs_lo + (size_t)NC * ND);    // 4 KB

  prep_centers<<<dim3(NC), dim3(64), 0, stream>>>(centers, cs_hi, cs_lo, csq);
  kmeans_fused<<<dim3(NROWS / BM), dim3(1024), 0, stream>>>(x, cs_hi, cs_lo, csq,
                                                            dist, prob);
}

// Round 4
// 717.605 us; speedup vs baseline: 2.9584x; 2.9584x over previous
//
#include <hip/hip_runtime.h>
#include <stdint.h>

#define NROWS 131072
#define NC 1024
#define ND 512
#define BM 32

using f32x4   = __attribute__((ext_vector_type(4))) float;
using bf16x8  = __attribute__((ext_vector_type(8))) short;
using short2v = __attribute__((ext_vector_type(2))) short;
using float2v = __attribute__((ext_vector_type(2))) float;
using float4v = __attribute__((ext_vector_type(4))) float;

__device__ __forceinline__ uint16_t f32_bf16(float f) {
  uint32_t u = __builtin_bit_cast(uint32_t, f);
  u += 0x7FFFu + ((u >> 16) & 1u);   // RNE
  return (uint16_t)(u >> 16);
}
__device__ __forceinline__ float bf16_f32(uint16_t h) {
  uint32_t u = ((uint32_t)h) << 16;
  return __builtin_bit_cast(float, u);
}

__device__ __forceinline__ void gload_lds16(const void* g, void* l) {
  __builtin_amdgcn_global_load_lds(
      (const __attribute__((address_space(1))) unsigned int*)g,
      (__attribute__((address_space(3))) unsigned int*)l, 16, 0, 0);
}

// ---------------------------------------------------------------------------
// Prep: split centers into bf16 hi/lo, pre-permuted so each 32-k slice is a
// contiguous 64KB block whose LINEAR copy into LDS yields the swizzled layout:
// LDS[c*64 + p*16 + b] holds logical chunk j = p ^ (c&3) of row c.
// Also computes csq[c] in fp32.
// ---------------------------------------------------------------------------
__global__ __launch_bounds__(64) void prep_centers(
    const float* __restrict__ centers,
    uint16_t* __restrict__ cs_hi, uint16_t* __restrict__ cs_lo,
    float* __restrict__ csq) {
  const int c = blockIdx.x;   // 1024
  const int t = threadIdx.x;  // 64
  const float* row = centers + (size_t)c * ND;
  const int k0 = t * 8;
  float v[8];
#pragma unroll
  for (int i = 0; i < 8; ++i) v[i] = row[k0 + i];
  float ss = 0.f;
#pragma unroll
  for (int i = 0; i < 8; ++i) ss += v[i] * v[i];
#pragma unroll
  for (int m = 1; m < 64; m <<= 1) ss += __shfl_xor(ss, m);
  if (t == 0) csq[c] = ss;

  const int kk = t >> 2;          // K-step 0..15
  const int j  = t & 3;           // logical 16B chunk within K-step
  const int p  = j ^ (c & 3);     // physical chunk (XOR swizzle)
  const size_t off = (size_t)kk * 32768 + (size_t)c * 32 + (size_t)p * 8;
#pragma unroll
  for (int i = 0; i < 8; ++i) {
    uint16_t h = f32_bf16(v[i]);
    uint16_t l = f32_bf16(v[i] - bf16_f32(h));
    cs_hi[off + i] = h;
    cs_lo[off + i] = l;
  }
}

// ---------------------------------------------------------------------------
// Fused kernel: 32 rows x full 1024 cols per block. 8 waves, each 32x128
// (acc = 64 VGPR -> no spill). Single-buffered Bs (64KB) + As (2x2KB) ->
// ~70KB LDS -> 2 blocks/CU for cross-block latency hiding.
// Pass H (s<16): B=cs_hi, acc += a_hi*b + a_lo*b  (xsq fused here)
// Pass L (s<16): B=cs_lo, acc += a_hi*b
// Epilogue: LDS transpose + row-local softmax + contiguous float4 stores.
// ---------------------------------------------------------------------------
__global__ __launch_bounds__(512)
__attribute__((amdgpu_waves_per_eu(4)))
void kmeans_fused(
    const float* __restrict__ x,
    const uint16_t* __restrict__ cs_hi, const uint16_t* __restrict__ cs_lo,
    const float* __restrict__ csq,
    float* __restrict__ dist, float* __restrict__ prob) {
  __shared__ __align__(16) char bs[65536];    // 1024 cols x 32 bf16, swizzled
  __shared__ __align__(16) char as_hi[2048];  // 32 rows x 32 bf16, swizzled
  __shared__ __align__(16) char as_lo[2048];
  __shared__ float xsq[BM];

  const int tid  = threadIdx.x;
  const int lane = tid & 63;
  const int wid  = tid >> 6;   // 0..7 -> cols wid*128
  const int row0 = blockIdx.x * BM;
  const int ar = tid >> 4;     // staging row 0..31
  const int ac = tid & 15;     // staging col-chunk

  auto stage = [&](const uint16_t* base, int kk) {
    const char* srcb = (const char*)(base + (size_t)kk * 32768);
#pragma unroll
    for (int i = 0; i < 8; ++i) {
      const int o = (tid + i * 512) * 16;
      gload_lds16(srcb + o, bs + o);
    }
  };
  auto xload = [&](int kk) -> float2v {
    return *(const float2v*)(x + (size_t)(row0 + ar) * ND + kk * 32 + ac * 2);
  };
  auto awrite = [&](float2v v) {
    const int p = (ac >> 2) ^ (ar & 3);
    const int off = ar * 64 + p * 16 + (ac & 3) * 4;
    short2v h, l;
#pragma unroll
    for (int i = 0; i < 2; ++i) {
      uint16_t hb = f32_bf16(v[i]);
      h[i] = (short)hb;
      l[i] = (short)f32_bf16(v[i] - bf16_f32(hb));
    }
    *(short2v*)(as_hi + off) = h;
    *(short2v*)(as_lo + off) = l;
  };

  f32x4 acc[2][8];
  const f32x4 z = {0.f, 0.f, 0.f, 0.f};
#pragma unroll
  for (int mr = 0; mr < 2; ++mr)
#pragma unroll
    for (int n = 0; n < 8; ++n) acc[mr][n] = z;

  // fragment LDS byte offsets (row&3 == lane&3 since bases are mult of 16)
  const int swz  = (((lane >> 4) ^ (lane & 3)) << 4);
  const int aoff = (lane & 15) * 64 + swz;               // + mr*1024
  const int boff = (wid * 128 + (lane & 15)) * 64 + swz; // + n*1024

  float xacc = 0.f;

  // ---- pass H: B = cs_hi, acc += a_hi*b + a_lo*b ----
#pragma unroll 1
  for (int s = 0; s < 16; ++s) {
    stage(cs_hi, s);
    float2v v = xload(s);
    awrite(v);
    xacc += v[0] * v[0] + v[1] * v[1];
    __syncthreads();
    {
      bf16x8 ah0 = *(const bf16x8*)(as_hi + aoff);
      bf16x8 ah1 = *(const bf16x8*)(as_hi + aoff + 1024);
      bf16x8 al0 = *(const bf16x8*)(as_lo + aoff);
      bf16x8 al1 = *(const bf16x8*)(as_lo + aoff + 1024);
#pragma unroll
      for (int n = 0; n < 8; ++n) {
        bf16x8 b = *(const bf16x8*)(bs + boff + n * 1024);
        acc[0][n] = __builtin_amdgcn_mfma_f32_16x16x32_bf16(ah0, b, acc[0][n], 0, 0, 0);
        acc[1][n] = __builtin_amdgcn_mfma_f32_16x16x32_bf16(ah1, b, acc[1][n], 0, 0, 0);
        acc[0][n] = __builtin_amdgcn_mfma_f32_16x16x32_bf16(al0, b, acc[0][n], 0, 0, 0);
        acc[1][n] = __builtin_amdgcn_mfma_f32_16x16x32_bf16(al1, b, acc[1][n], 0, 0, 0);
      }
    }
    __syncthreads();
  }

  // ---- pass L: B = cs_lo, acc += a_hi*b ----
#pragma unroll 1
  for (int s = 0; s < 16; ++s) {
    stage(cs_lo, s);
    float2v v = xload(s);   // re-read x tile (L2-hot) to rebuild a_hi
    awrite(v);
    __syncthreads();
    {
      bf16x8 ah0 = *(const bf16x8*)(as_hi + aoff);
      bf16x8 ah1 = *(const bf16x8*)(as_hi + aoff + 1024);
#pragma unroll
      for (int n = 0; n < 8; ++n) {
        bf16x8 b = *(const bf16x8*)(bs + boff + n * 1024);
        acc[0][n] = __builtin_amdgcn_mfma_f32_16x16x32_bf16(ah0, b, acc[0][n], 0, 0, 0);
        acc[1][n] = __builtin_amdgcn_mfma_f32_16x16x32_bf16(ah1, b, acc[1][n], 0, 0, 0);
      }
    }
    __syncthreads();
  }

  // ---- xsq finalize: reduce over the 16 threads sharing row ar ----
  xacc += __shfl_xor(xacc, 1);
  xacc += __shfl_xor(xacc, 2);
  xacc += __shfl_xor(xacc, 4);
  xacc += __shfl_xor(xacc, 8);
  if (ac == 0) xsq[ar] = xacc;

  // ---- epilogue: LDS transpose (16 rows/pass) + row-local softmax ----
  float* ldsT = (float*)bs;   // 16 x 1024 fp32 = 64KB
  const int rsub = (lane >> 4) * 4;
#pragma unroll
  for (int p = 0; p < 2; ++p) {
#pragma unroll
    for (int n = 0; n < 8; ++n)
#pragma unroll
      for (int r = 0; r < 4; ++r) {
        const int lrow = rsub + r;
        const int col = wid * 128 + n * 16 + (lane & 15);
        ldsT[lrow * 1024 + (col ^ (((lrow >> 2) & 3) << 3))] = acc[p][n][r];
      }
    __syncthreads();
#pragma unroll
    for (int q = 0; q < 2; ++q) {
      const int lr = wid * 2 + q;          // one wave -> 2 rows per pass
      const size_t grow = (size_t)(row0 + p * 16 + lr);
      const int cmask = ((lr >> 2) & 3) << 3;
      const float xq = xsq[p * 16 + lr];
      float4v dd[4];
      float dmin = 1e30f;
#pragma unroll
      for (int j = 0; j < 4; ++j) {
        const int f = lane * 4 + j * 256;
        float4v raw = *(const float4v*)&ldsT[lr * 1024 + (f ^ cmask)];
        float4v cq = *(const float4v*)(csq + f);
#pragma unroll
        for (int i = 0; i < 4; ++i) {
          float d = fmaxf(xq + cq[i] - 2.0f * raw[i], 0.0f);
          dd[j][i] = d;
          dmin = fminf(dmin, d);
        }
      }
#pragma unroll
      for (int m = 1; m < 64; m <<= 1) dmin = fminf(dmin, __shfl_xor(dmin, m));
#pragma unroll
      for (int j = 0; j < 4; ++j)
        *(float4v*)(dist + grow * NC + lane * 4 + j * 256) = dd[j];
      float ssum = 0.f;
#pragma unroll
      for (int j = 0; j < 4; ++j)
#pragma unroll
        for (int i = 0; i < 4; ++i) {
          float e = __expf(dmin - dd[j][i]);
          dd[j][i] = e;
          ssum += e;
        }
#pragma unroll
      for (int m = 1; m < 64; m <<= 1) ssum += __shfl_xor(ssum, m);
      const float sinv = 1.0f / ssum;
#pragma unroll
      for (int j = 0; j < 4; ++j) {
        float4v pv;
#pragma unroll
        for (int i = 0; i < 4; ++i) pv[i] = dd[j][i] * sinv;
        *(float4v*)(prob + grow * NC + lane * 4 + j * 256) = pv;
      }
    }
    __syncthreads();
  }
}

extern "C" void kernel_launch(void* const* d_in, const int* in_sizes, int n_in,
                              void* d_out, int out_size, void* d_ws, size_t ws_size,
                              hipStream_t stream) {
  const float* x = (const float*)d_in[0];
  const float* centers = (const float*)d_in[1];
  float* dist = (float*)d_out;
  float* prob = dist + (size_t)NROWS * NC;

  uint16_t* cs_hi = (uint16_t*)d_ws;                 // 1 MB
  uint16_t* cs_lo = cs_hi + (size_t)NC * ND;         // 1 MB
  float* csq = (float*)(cs_lo + (size_t)NC * ND);    // 4 KB

  prep_centers<<<dim3(NC), dim3(64), 0, stream>>>(centers, cs_hi, cs_lo, csq);
  kmeans_fused<<<dim3(NROWS / BM), dim3(512), 0, stream>>>(x, cs_hi, cs_lo, csq,
                                                           dist, prob);
}